// Round 7
// baseline (125.214 us; speedup 1.0000x reference)
//
#include <hip/hip_runtime.h>
#include <cmath>

// Problem constants (B=4,S=1024,D=1024,O=1024,E=8,R=16,TOP_K=2)
#define M_TOK 4096
#define KD    1024
#define KEXT  1152     // 1024 + E*R
#define NOUT  1024
#define ERDIM 128      // E*R
#define SCALING 2.0f   // 32/16

typedef short bf16x8 __attribute__((ext_vector_type(8)));
typedef float f32x4  __attribute__((ext_vector_type(4)));

__device__ __forceinline__ ushort f2bf(float f) {
    union { float f; unsigned u; } v; v.f = f;
    unsigned r = v.u + 0x7fffu + ((v.u >> 16) & 1u);
    return (ushort)(r >> 16);
}
__device__ __forceinline__ float b2f(ushort u) {
    union { unsigned u; float f; } v; v.u = ((unsigned)u) << 16;
    return v.f;
}

// async 16B global->LDS. C-style casts required for addrspace conversion.
typedef const unsigned int __attribute__((address_space(1)))* gas_ptr;
typedef unsigned int __attribute__((address_space(3)))* las_ptr;
__device__ __forceinline__ void gld_lds16(const ushort* g, ushort* l) {
    __builtin_amdgcn_global_load_lds((gas_ptr)g, (las_ptr)l, 16, 0, 0);
}

// Fragment-linear B layout: element (n,k) of an [N][K] B^T-operand matrix
// lives at ((n>>4)*KC + (k>>5))*512 + (((n&15) + 16*((k>>3)&3)))*8 + (k&7),
// KC = K/32.  A wave's MFMA B-fragment (16 n x 32 k) is then exactly
// base + lane*8 .. +8 — one coalesced global_load_dwordx4, no LDS needed.

// ---------------------------------------------------------------------------
// Fused: blocks [0,4096): per-token x->bf16 + fp32/fp64 router + top-2
//        softmax weights.  blocks [4096,9216): pack base_w / lora_B^T /
//        lora_A^T to bf16 in FRAG-LINEAR layout.
// Router reduction: transposed fold (7 fp64 exchanges) + 3 butterflies.
// ---------------------------------------------------------------------------
__global__ __launch_bounds__(256) void prep_router(
    const float* __restrict__ x, const float* __restrict__ rw,
    const float* __restrict__ rb, const float* __restrict__ base_w,
    const float* __restrict__ lora_A, const float* __restrict__ lora_B,
    ushort* __restrict__ Aext, ushort* __restrict__ Bpack,
    ushort* __restrict__ LATpack, float* __restrict__ wgt)
{
    const int tid = threadIdx.x;
    if (blockIdx.x >= 4096) {               // ---- pack path ----
        int i = (blockIdx.x - 4096) * 256 + tid;
        const int NB = NOUT * KEXT;         // 1,179,648
        if (i < NB) {
            int o = i / KEXT;               // n (output col)
            int c = i - o * KEXT;           // k
            float v = (c < KD) ? base_w[(size_t)o * KD + c]
                               : lora_B[(size_t)(c - KD) * NOUT + o];
            int lane = (o & 15) + ((c >> 3) & 3) * 16;
            int didx = (((o >> 4) * 36 + (c >> 5)) * 64 + lane) * 8 + (c & 7);
            Bpack[didx] = f2bf(v);
        } else {
            int j = i - NB;                 // 0 .. 131071
            int er = j >> 10, d = j & 1023; // n=er, k=d
            int e = er >> 4, r = er & 15;
            float v = lora_A[((size_t)e * KD + d) * 16 + r];
            int lane = (er & 15) + ((d >> 3) & 3) * 16;
            int didx = (((er >> 4) * 32 + (d >> 5)) * 64 + lane) * 8 + (d & 7);
            LATpack[didx] = f2bf(v);
        }
        return;
    }
    // ---- router/convert path ----
    const int t = blockIdx.x;
    const float4 xv = ((const float4*)(x + (size_t)t * KD))[tid];

    ushort4 xb;
    xb.x = f2bf(xv.x); xb.y = f2bf(xv.y); xb.z = f2bf(xv.z); xb.w = f2bf(xv.w);
    ((ushort4*)(Aext + (size_t)t * KEXT))[tid] = xb;

    double p[8];
    #pragma unroll
    for (int e = 0; e < 8; e++) {
        const float4 wv = ((const float4*)(rw + (size_t)e * KD))[tid];
        p[e] = (double)(xv.x * wv.x) + (double)(xv.y * wv.y) +
               (double)(xv.z * wv.z) + (double)(xv.w * wv.w);
    }

    const int wave = tid >> 6, lane = tid & 63;
    double q0, q1, q2, q3, r0, r1, s;
    {   const bool b = lane & 1;
        double s0 = b ? p[0] : p[1];
        double s1 = b ? p[2] : p[3];
        double s2 = b ? p[4] : p[5];
        double s3 = b ? p[6] : p[7];
        q0 = (b ? p[1] : p[0]) + __shfl_xor(s0, 1);
        q1 = (b ? p[3] : p[2]) + __shfl_xor(s1, 1);
        q2 = (b ? p[5] : p[4]) + __shfl_xor(s2, 1);
        q3 = (b ? p[7] : p[6]) + __shfl_xor(s3, 1);
    }
    {   const bool b = (lane >> 1) & 1;
        double s0 = b ? q0 : q1;
        double s1 = b ? q2 : q3;
        r0 = (b ? q1 : q0) + __shfl_xor(s0, 2);
        r1 = (b ? q3 : q2) + __shfl_xor(s1, 2);
    }
    {   const bool b = (lane >> 2) & 1;
        double s0 = b ? r0 : r1;
        s = (b ? r1 : r0) + __shfl_xor(s0, 4);
    }
    s += __shfl_xor(s, 8);
    s += __shfl_xor(s, 16);
    s += __shfl_xor(s, 32);

    __shared__ double red[4][8];
    __shared__ float  lg[8];
    if (lane < 8) red[wave][lane] = s;
    __syncthreads();
    if (tid < 8) {
        double sum = red[0][tid] + red[1][tid] + red[2][tid] + red[3][tid]
                   + (double)rb[tid];
        lg[tid] = (float)sum;
    }
    __syncthreads();
    if (tid < 8) {
        float my = lg[tid];
        float m1 = -INFINITY, m2 = -INFINITY;
        #pragma unroll
        for (int i = 0; i < 8; i++) {
            float v = lg[i];
            if (v > m1) { m2 = m1; m1 = v; }
            else if (v > m2) { m2 = v; }
        }
        float denom = 0.f;
        #pragma unroll
        for (int i = 0; i < 8; i++)
            if (lg[i] >= m2) denom += expf(lg[i] - m1);
        float w = (my >= m2) ? expf(my - m1) / denom : 0.f;
        wgt[t * 8 + tid] = SCALING * w;
    }
}

// ---------------------------------------------------------------------------
// Main GEMM: out = Aext @ Bext^T + bias. Tile 128x64, grid (32,16)=512
// -> 2 blocks/CU. LDS only for A (32 KB dbuf, XOR swizzle); B-frags loaded
// directly from frag-linear Bpack (coalesced dwordx4, L2-resident) and
// interleaved with MFMA by the scheduler. 4 waves of 32x64.
// ---------------------------------------------------------------------------
__global__ __launch_bounds__(256) void gemm_main(
    const ushort* __restrict__ A, const ushort* __restrict__ Bp,
    float* __restrict__ C, const float* __restrict__ bias)
{
    __shared__ __attribute__((aligned(16))) ushort As[2][128 * 64];

    const int tid  = threadIdx.x;
    const int wave = tid >> 6;
    const int lane = tid & 63;
    const int m0  = blockIdx.x * 128;
    const int ntb = blockIdx.y * 4;          // n0 = ntb*16

    const int srow = tid >> 3;               // 0..31
    const int scol = ((tid & 7) ^ (srow & 7)) * 8;
    const ushort* aP = A + (size_t)(m0 + srow) * KEXT + scol;

    const int wr = wave * 32;
    const int fm = lane & 15;
    const int q  = lane >> 4;
    const int rx = fm & 7;

    const ushort* bBase = Bp + (size_t)lane * 8;

    f32x4 acc[2][4] = {};

    auto stageA = [&](int buf, int kk) {
        ushort* d = &As[buf][tid * 8];
        #pragma unroll
        for (int p = 0; p < 4; p++)
            gld_lds16(aP + kk + (size_t)(p * 32) * KEXT, d + p * 2048);
    };

    stageA(0, 0);

    for (int ks = 0; ks < 18; ++ks) {
        __syncthreads();   // A buf[ks&1] staged (vmcnt drained)
        if (ks + 1 < 18)
            stageA((ks + 1) & 1, (ks + 1) * 64);

        // B fragments direct from global (frag-linear): kc = ks*2+kh
        bf16x8 bf[2][4];
        #pragma unroll
        for (int kh = 0; kh < 2; kh++)
            #pragma unroll
            for (int ni = 0; ni < 4; ni++)
                bf[kh][ni] = *(const bf16x8*)(bBase +
                    (size_t)((ntb + ni) * 36 + ks * 2 + kh) * 512);

        const ushort* as = &As[ks & 1][0];
        bf16x8 af[2][2];
        #pragma unroll
        for (int kh = 0; kh < 2; kh++) {
            const int sg = ((kh * 4 + q) ^ rx) * 8;
            #pragma unroll
            for (int i = 0; i < 2; i++)
                af[kh][i] = *(const bf16x8*)&as[(wr + i * 16 + fm) * 64 + sg];
        }
        #pragma unroll
        for (int kh = 0; kh < 2; kh++)
            #pragma unroll
            for (int mi = 0; mi < 2; mi++)
                #pragma unroll
                for (int ni = 0; ni < 4; ni++)
                    acc[mi][ni] = __builtin_amdgcn_mfma_f32_16x16x32_bf16(
                        af[kh][mi], bf[kh][ni], acc[mi][ni], 0, 0, 0);
    }

    // C/D layout: col = lane&15, row = (lane>>4)*4 + reg   [m89/m91 verified]
    const int rr = q * 4;
    #pragma unroll
    for (int ni = 0; ni < 4; ni++) {
        const int col = (ntb + ni) * 16 + fm;
        const float bv = bias[col];
        #pragma unroll
        for (int mi = 0; mi < 2; mi++) {
            const int row = m0 + wr + mi * 16 + rr;
            #pragma unroll
            for (int r = 0; r < 4; r++)
                C[(size_t)(row + r) * NOUT + col] = acc[mi][ni][r] + bv;
        }
    }
}

// ---------------------------------------------------------------------------
// ax GEMM (split-K=4): bf16 partials = (x @ lora_A) slab. Tile 64x128,
// grid (64,1,4) -> 256 blocks. LDS only for A (16 KB dbuf); LAT frags
// direct from frag-linear LATpack. 4 waves of 32x64.
// ---------------------------------------------------------------------------
__global__ __launch_bounds__(256) void gemm_ax(
    const ushort* __restrict__ A, const ushort* __restrict__ Lp,
    ushort* __restrict__ part)
{
    __shared__ __attribute__((aligned(16))) ushort As[2][64 * 64];

    const int tid  = threadIdx.x;
    const int wave = tid >> 6;
    const int lane = tid & 63;
    const int m0  = blockIdx.x * 64;
    const int kc0 = blockIdx.z * 8;          // k0 = bz*256
    part += (size_t)blockIdx.z * (M_TOK * ERDIM);

    const int srow = tid >> 3;
    const int scol = ((tid & 7) ^ (srow & 7)) * 8;
    const ushort* aP = A + (size_t)(m0 + srow) * KEXT + kc0 * 32 + scol;

    const int wr = (wave >> 1) * 32;
    const int wc = (wave & 1) * 64;
    const int fm = lane & 15;
    const int q  = lane >> 4;
    const int rx = fm & 7;

    const ushort* lBase = Lp + (size_t)lane * 8;
    const int ntw = (wave & 1) * 4;          // LAT n-tile base for this wave

    f32x4 acc[2][4] = {};

    auto stageA = [&](int buf, int kk) {
        ushort* d = &As[buf][tid * 8];
        #pragma unroll
        for (int p = 0; p < 2; p++)
            gld_lds16(aP + kk + (size_t)(p * 32) * KEXT, d + p * 2048);
    };

    stageA(0, 0);

    for (int ks = 0; ks < 4; ++ks) {
        __syncthreads();
        if (ks + 1 < 4)
            stageA((ks + 1) & 1, (ks + 1) * 64);

        bf16x8 bf[2][4];
        #pragma unroll
        for (int kh = 0; kh < 2; kh++)
            #pragma unroll
            for (int ni = 0; ni < 4; ni++)
                bf[kh][ni] = *(const bf16x8*)(lBase +
                    (size_t)((ntw + ni) * 32 + kc0 + ks * 2 + kh) * 512);

        const ushort* as = &As[ks & 1][0];
        bf16x8 af[2][2];
        #pragma unroll
        for (int kh = 0; kh < 2; kh++) {
            const int sg = ((kh * 4 + q) ^ rx) * 8;
            #pragma unroll
            for (int i = 0; i < 2; i++)
                af[kh][i] = *(const bf16x8*)&as[(wr + i * 16 + fm) * 64 + sg];
        }
        #pragma unroll
        for (int kh = 0; kh < 2; kh++)
            #pragma unroll
            for (int mi = 0; mi < 2; mi++)
                #pragma unroll
                for (int ni = 0; ni < 4; ni++)
                    acc[mi][ni] = __builtin_amdgcn_mfma_f32_16x16x32_bf16(
                        af[kh][mi], bf[kh][ni], acc[mi][ni], 0, 0, 0);
    }

    const int rr = q * 4;
    #pragma unroll
    for (int ni = 0; ni < 4; ni++) {
        const int col = wc + ni * 16 + fm;
        #pragma unroll
        for (int mi = 0; mi < 2; mi++) {
            const int row = m0 + wr + mi * 16 + rr;
            #pragma unroll
            for (int r = 0; r < 4; r++)
                part[(size_t)(row + r) * ERDIM + col] = f2bf(acc[mi][ni][r]);
        }
    }
}

// ---------------------------------------------------------------------------
// Reduce bf16 split-K partials (4 slabs), apply SCALING*softmax weight,
// write bf16 into Aext[:,1024:1152]. ushort8-vectorized (8 er per thread;
// e = er>>4 is constant within an aligned 8-group).
// ---------------------------------------------------------------------------
__global__ __launch_bounds__(256) void ax_combine(
    const ushort* __restrict__ part, const float* __restrict__ wgt,
    ushort* __restrict__ Aext)
{
    int g = blockIdx.x * 256 + threadIdx.x;   // 0 .. 65535 (8-elem groups)
    const int t = g >> 4, gr = g & 15;
    const int er0 = gr * 8;
    const int SL = M_TOK * ERDIM;             // 524288
    const int base = t * ERDIM + er0;

    ushort4 p0a = *(const ushort4*)(part + base);
    ushort4 p0b = *(const ushort4*)(part + base + 4);
    ushort4 p1a = *(const ushort4*)(part + base + SL);
    ushort4 p1b = *(const ushort4*)(part + base + SL + 4);
    ushort4 p2a = *(const ushort4*)(part + base + 2 * SL);
    ushort4 p2b = *(const ushort4*)(part + base + 2 * SL + 4);
    ushort4 p3a = *(const ushort4*)(part + base + 3 * SL);
    ushort4 p3b = *(const ushort4*)(part + base + 3 * SL + 4);

    const float w = wgt[t * 8 + (er0 >> 4)];
    ushort o[8];
    o[0] = f2bf((b2f(p0a.x) + b2f(p1a.x) + b2f(p2a.x) + b2f(p3a.x)) * w);
    o[1] = f2bf((b2f(p0a.y) + b2f(p1a.y) + b2f(p2a.y) + b2f(p3a.y)) * w);
    o[2] = f2bf((b2f(p0a.z) + b2f(p1a.z) + b2f(p2a.z) + b2f(p3a.z)) * w);
    o[3] = f2bf((b2f(p0a.w) + b2f(p1a.w) + b2f(p2a.w) + b2f(p3a.w)) * w);
    o[4] = f2bf((b2f(p0b.x) + b2f(p1b.x) + b2f(p2b.x) + b2f(p3b.x)) * w);
    o[5] = f2bf((b2f(p0b.y) + b2f(p1b.y) + b2f(p2b.y) + b2f(p3b.y)) * w);
    o[6] = f2bf((b2f(p0b.z) + b2f(p1b.z) + b2f(p2b.z) + b2f(p3b.z)) * w);
    o[7] = f2bf((b2f(p0b.w) + b2f(p1b.w) + b2f(p2b.w) + b2f(p3b.w)) * w);

    ushort* dst = Aext + (size_t)t * KEXT + KD + er0;
    ((ushort4*)dst)[0] = *(ushort4*)&o[0];
    ((ushort4*)dst)[1] = *(ushort4*)&o[4];
}

// ---------------------------------------------------------------------------
extern "C" void kernel_launch(void* const* d_in, const int* in_sizes, int n_in,
                              void* d_out, int out_size, void* d_ws, size_t ws_size,
                              hipStream_t stream) {
    const float* x        = (const float*)d_in[0];
    const float* base_w   = (const float*)d_in[1];
    const float* base_b   = (const float*)d_in[2];
    const float* lora_A   = (const float*)d_in[3];
    const float* lora_B   = (const float*)d_in[4];
    const float* router_w = (const float*)d_in[5];
    const float* router_b = (const float*)d_in[6];
    float* out = (float*)d_out;

    // workspace layout (bytes): total ~16.4 MB
    char* ws = (char*)d_ws;
    ushort* Aext    = (ushort*)(ws);             // 4096*1152*2 = 9,437,184
    ushort* Bpack   = (ushort*)(ws + 9437184);   // 1024*1152*2 = 2,359,296
    ushort* LATpack = (ushort*)(ws + 11796480);  //  128*1024*2 =   262,144
    float*  wgt     = (float*) (ws + 12058624);  //   4096*8*4  =   131,072
    ushort* part    = (ushort*)(ws + 12189696);  // 4*4096*128*2= 4,194,304

    // 1. fused: x->bf16 + router weights (blocks 0..4095) and frag-linear
    //    bf16 packing of base_w / lora_B^T / lora_A^T (blocks 4096..9215)
    prep_router<<<9216, 256, 0, stream>>>(
        x, router_w, router_b, base_w, lora_A, lora_B,
        Aext, Bpack, LATpack, wgt);
    // 2. ax = x @ lora_A  (M=4096,N=128,K=1024) split-K=4 -> bf16 partials
    gemm_ax<<<dim3(64, 1, 4), 256, 0, stream>>>(Aext, LATpack, part);
    // 3. sax = bf16(SCALING * w * ax) into Aext[:,1024:1152]
    ax_combine<<<256, 256, 0, stream>>>(part, wgt, Aext);
    // 4. out = [x|sax] @ [base_w|lora_B^T]^T + bias  (M=4096,N=1024,K=1152)
    gemm_main<<<dim3(32, 16), 256, 0, stream>>>(Aext, Bpack, out, base_b);
}

// Round 8
// 112.191 us; speedup vs baseline: 1.1161x; 1.1161x over previous
//
#include <hip/hip_runtime.h>
#include <cmath>

// Problem constants (B=4,S=1024,D=1024,O=1024,E=8,R=16,TOP_K=2)
#define M_TOK 4096
#define KD    1024
#define KEXT  1152     // 1024 + E*R
#define NOUT  1024
#define ERDIM 128      // E*R
#define SCALING 2.0f   // 32/16

typedef short bf16x8 __attribute__((ext_vector_type(8)));
typedef float f32x4  __attribute__((ext_vector_type(4)));

__device__ __forceinline__ ushort f2bf(float f) {
    union { float f; unsigned u; } v; v.f = f;
    unsigned r = v.u + 0x7fffu + ((v.u >> 16) & 1u);
    return (ushort)(r >> 16);
}
__device__ __forceinline__ float b2f(ushort u) {
    union { unsigned u; float f; } v; v.u = ((unsigned)u) << 16;
    return v.f;
}

// async 16B global->LDS. C-style casts required for addrspace conversion.
typedef const unsigned int __attribute__((address_space(1)))* gas_ptr;
typedef unsigned int __attribute__((address_space(3)))* las_ptr;
__device__ __forceinline__ void gld_lds16(const ushort* g, ushort* l) {
    __builtin_amdgcn_global_load_lds((gas_ptr)g, (las_ptr)l, 16, 0, 0);
}

// Fragment-linear B layout: element (n,k) of an [N][K] B^T-operand matrix
// lives at ((n>>4)*KC + (k>>5))*512 + ((n&15) + 16*((k>>3)&3))*8 + (k&7).
// A wave's MFMA B-fragment (16n x 32k) = base + lane*8 .. +8: one coalesced
// global_load_dwordx4 per fragment, no LDS round-trip.

// ---------------------------------------------------------------------------
// Fused prep: blocks [0,4096): per-token x->bf16 + fp64 router + top-2
// softmax weights.  blocks [4096,4736): DEST-LINEAR frag pack of base_w /
// lora_B^T (Bpack) and lora_A^T (LATpack) — coalesced ushort8 writes,
// inverse-permuted reads.
// ---------------------------------------------------------------------------
__global__ __launch_bounds__(256) void prep_router(
    const float* __restrict__ x, const float* __restrict__ rw,
    const float* __restrict__ rb, const float* __restrict__ base_w,
    const float* __restrict__ lora_A, const float* __restrict__ lora_B,
    ushort* __restrict__ Aext, ushort* __restrict__ Bpack,
    ushort* __restrict__ LATpack, float* __restrict__ wgt)
{
    const int tid = threadIdx.x;
    if (blockIdx.x >= 4096) {               // ---- pack path (dest-linear) ----
        int tix = (blockIdx.x - 4096) * 256 + tid;   // 0 .. 163839
        ushort v[8];
        if (tix < 147456) {                 // Bpack: 8 elems at tix*8
            const int lane = tix & 63;
            const int tile = tix >> 6;      // ot*36 + kc
            const int kc = tile % 36, ot = tile / 36;
            const int o  = ot * 16 + (lane & 15);
            const int c0 = kc * 32 + (lane >> 4) * 8;
            if (c0 < KD) {
                const float4* src = (const float4*)(base_w + (size_t)o * KD + c0);
                float4 f0 = src[0], f1 = src[1];
                v[0]=f2bf(f0.x); v[1]=f2bf(f0.y); v[2]=f2bf(f0.z); v[3]=f2bf(f0.w);
                v[4]=f2bf(f1.x); v[5]=f2bf(f1.y); v[6]=f2bf(f1.z); v[7]=f2bf(f1.w);
            } else {
                #pragma unroll
                for (int t = 0; t < 8; t++)
                    v[t] = f2bf(lora_B[(size_t)(c0 + t - KD) * NOUT + o]);
            }
            ushort* dst = Bpack + (size_t)tix * 8;
            ((ushort4*)dst)[0] = *(ushort4*)&v[0];
            ((ushort4*)dst)[1] = *(ushort4*)&v[4];
        } else {                            // LATpack
            const int tix2 = tix - 147456;  // 0 .. 16383
            const int lane = tix2 & 63;
            const int tile = tix2 >> 6;     // nt*32 + kc
            const int kc = tile & 31, nt = tile >> 5;
            const int er = nt * 16 + (lane & 15);
            const int d0 = kc * 32 + (lane >> 4) * 8;
            const int e = er >> 4, r = er & 15;
            #pragma unroll
            for (int t = 0; t < 8; t++)
                v[t] = f2bf(lora_A[((size_t)e * KD + d0 + t) * 16 + r]);
            ushort* dst = LATpack + (size_t)tix2 * 8;
            ((ushort4*)dst)[0] = *(ushort4*)&v[0];
            ((ushort4*)dst)[1] = *(ushort4*)&v[4];
        }
        return;
    }
    // ---- router/convert path ----
    const int t = blockIdx.x;
    const float4 xv = ((const float4*)(x + (size_t)t * KD))[tid];

    ushort4 xb;
    xb.x = f2bf(xv.x); xb.y = f2bf(xv.y); xb.z = f2bf(xv.z); xb.w = f2bf(xv.w);
    ((ushort4*)(Aext + (size_t)t * KEXT))[tid] = xb;

    double p[8];
    #pragma unroll
    for (int e = 0; e < 8; e++) {
        const float4 wv = ((const float4*)(rw + (size_t)e * KD))[tid];
        p[e] = (double)(xv.x * wv.x) + (double)(xv.y * wv.y) +
               (double)(xv.z * wv.z) + (double)(xv.w * wv.w);
    }

    const int wave = tid >> 6, lane = tid & 63;
    // transposed fold: after 3 levels lane l holds expert l&7 (R5 win)
    double q0, q1, q2, q3, r0, r1, s;
    {   const bool b = lane & 1;
        double s0 = b ? p[0] : p[1];
        double s1 = b ? p[2] : p[3];
        double s2 = b ? p[4] : p[5];
        double s3 = b ? p[6] : p[7];
        q0 = (b ? p[1] : p[0]) + __shfl_xor(s0, 1);
        q1 = (b ? p[3] : p[2]) + __shfl_xor(s1, 1);
        q2 = (b ? p[5] : p[4]) + __shfl_xor(s2, 1);
        q3 = (b ? p[7] : p[6]) + __shfl_xor(s3, 1);
    }
    {   const bool b = (lane >> 1) & 1;
        double s0 = b ? q0 : q1;
        double s1 = b ? q2 : q3;
        r0 = (b ? q1 : q0) + __shfl_xor(s0, 2);
        r1 = (b ? q3 : q2) + __shfl_xor(s1, 2);
    }
    {   const bool b = (lane >> 2) & 1;
        double s0 = b ? r0 : r1;
        s = (b ? r1 : r0) + __shfl_xor(s0, 4);
    }
    s += __shfl_xor(s, 8);
    s += __shfl_xor(s, 16);
    s += __shfl_xor(s, 32);

    __shared__ double red[4][8];
    __shared__ float  lg[8];
    if (lane < 8) red[wave][lane] = s;
    __syncthreads();
    if (tid < 8) {
        double sum = red[0][tid] + red[1][tid] + red[2][tid] + red[3][tid]
                   + (double)rb[tid];
        lg[tid] = (float)sum;
    }
    __syncthreads();
    if (tid < 8) {
        float my = lg[tid];
        float m1 = -INFINITY, m2 = -INFINITY;
        #pragma unroll
        for (int i = 0; i < 8; i++) {
            float v = lg[i];
            if (v > m1) { m2 = m1; m1 = v; }
            else if (v > m2) { m2 = v; }
        }
        float denom = 0.f;
        #pragma unroll
        for (int i = 0; i < 8; i++)
            if (lg[i] >= m2) denom += expf(lg[i] - m1);
        float w = (my >= m2) ? expf(my - m1) / denom : 0.f;
        wgt[t * 8 + tid] = SCALING * w;
    }
}

// ---------------------------------------------------------------------------
// Main GEMM: out = Aext @ Bext^T + bias. Tile 128x64, grid (32,16)=512
// -> 2 blocks/CU. A via LDS dbuf (XOR swizzle); B via REGISTER-PIPELINED
// direct loads from frag-linear Bpack: bfc (consumed, barrier-drained) /
// bfn (next step, loaded right after barrier -> full iteration to land).
// No vmcnt waits on the MFMA path.
// ---------------------------------------------------------------------------
__global__ __launch_bounds__(256) void gemm_main(
    const ushort* __restrict__ A, const ushort* __restrict__ Bp,
    float* __restrict__ C, const float* __restrict__ bias)
{
    __shared__ __attribute__((aligned(16))) ushort As[2][128 * 64];

    const int tid  = threadIdx.x;
    const int wave = tid >> 6;
    const int lane = tid & 63;
    const int m0  = blockIdx.x * 128;
    const int ntb = blockIdx.y * 4;

    const int srow = tid >> 3;
    const int scol = ((tid & 7) ^ (srow & 7)) * 8;
    const ushort* aP = A + (size_t)(m0 + srow) * KEXT + scol;

    const int wr = wave * 32;
    const int fm = lane & 15;
    const int q  = lane >> 4;
    const int rx = fm & 7;

    const ushort* bBase = Bp + (size_t)lane * 8;

    f32x4 acc[2][4] = {};

    auto stageA = [&](int buf, int kk) {
        ushort* d = &As[buf][tid * 8];
        #pragma unroll
        for (int p = 0; p < 4; p++)
            gld_lds16(aP + kk + (size_t)(p * 32) * KEXT, d + p * 2048);
    };
    auto loadB = [&](bf16x8 (&bf)[2][4], int ks) {
        #pragma unroll
        for (int kh = 0; kh < 2; kh++)
            #pragma unroll
            for (int ni = 0; ni < 4; ni++)
                bf[kh][ni] = *(const bf16x8*)(bBase +
                    (size_t)((ntb + ni) * 36 + ks * 2 + kh) * 512);
    };

    bf16x8 bfc[2][4], bfn[2][4];
    stageA(0, 0);
    loadB(bfc, 0);

    for (int ks = 0; ks < 18; ++ks) {
        __syncthreads();            // As[ks&1] + bfc fully resident
        if (ks + 1 < 18) {
            loadB(bfn, ks + 1);     // lands by next barrier (hidden)
            stageA((ks + 1) & 1, (ks + 1) * 64);
        }
        const ushort* as = &As[ks & 1][0];
        bf16x8 af[2][2];
        #pragma unroll
        for (int kh = 0; kh < 2; kh++) {
            const int sg = ((kh * 4 + q) ^ rx) * 8;
            #pragma unroll
            for (int i = 0; i < 2; i++)
                af[kh][i] = *(const bf16x8*)&as[(wr + i * 16 + fm) * 64 + sg];
        }
        #pragma unroll
        for (int kh = 0; kh < 2; kh++)
            #pragma unroll
            for (int mi = 0; mi < 2; mi++)
                #pragma unroll
                for (int ni = 0; ni < 4; ni++)
                    acc[mi][ni] = __builtin_amdgcn_mfma_f32_16x16x32_bf16(
                        af[kh][mi], bfc[kh][ni], acc[mi][ni], 0, 0, 0);
        #pragma unroll
        for (int kh = 0; kh < 2; kh++)
            #pragma unroll
            for (int ni = 0; ni < 4; ni++)
                bfc[kh][ni] = bfn[kh][ni];
    }

    // C/D layout: col = lane&15, row = (lane>>4)*4 + reg   [m89/m91 verified]
    const int rr = q * 4;
    #pragma unroll
    for (int ni = 0; ni < 4; ni++) {
        const int col = (ntb + ni) * 16 + fm;
        const float bv = bias[col];
        #pragma unroll
        for (int mi = 0; mi < 2; mi++) {
            const int row = m0 + wr + mi * 16 + rr;
            #pragma unroll
            for (int r = 0; r < 4; r++)
                C[(size_t)(row + r) * NOUT + col] = acc[mi][ni][r] + bv;
        }
    }
}

// ---------------------------------------------------------------------------
// ax GEMM (split-K=4): bf16 partials of x @ lora_A. Tile 64x128, grid
// (64,1,4). A via LDS dbuf; LAT frags register-pipelined from LATpack.
// ---------------------------------------------------------------------------
__global__ __launch_bounds__(256) void gemm_ax(
    const ushort* __restrict__ A, const ushort* __restrict__ Lp,
    ushort* __restrict__ part)
{
    __shared__ __attribute__((aligned(16))) ushort As[2][64 * 64];

    const int tid  = threadIdx.x;
    const int wave = tid >> 6;
    const int lane = tid & 63;
    const int m0  = blockIdx.x * 64;
    const int kc0 = blockIdx.z * 8;
    part += (size_t)blockIdx.z * (M_TOK * ERDIM);

    const int srow = tid >> 3;
    const int scol = ((tid & 7) ^ (srow & 7)) * 8;
    const ushort* aP = A + (size_t)(m0 + srow) * KEXT + kc0 * 32 + scol;

    const int wr = (wave >> 1) * 32;
    const int wc = (wave & 1) * 64;
    const int fm = lane & 15;
    const int q  = lane >> 4;
    const int rx = fm & 7;

    const ushort* lBase = Lp + (size_t)lane * 8;
    const int ntw = (wave & 1) * 4;

    f32x4 acc[2][4] = {};

    auto stageA = [&](int buf, int kk) {
        ushort* d = &As[buf][tid * 8];
        #pragma unroll
        for (int p = 0; p < 2; p++)
            gld_lds16(aP + kk + (size_t)(p * 32) * KEXT, d + p * 2048);
    };
    auto loadB = [&](bf16x8 (&bf)[2][4], int ks) {
        #pragma unroll
        for (int kh = 0; kh < 2; kh++)
            #pragma unroll
            for (int ni = 0; ni < 4; ni++)
                bf[kh][ni] = *(const bf16x8*)(lBase +
                    (size_t)((ntw + ni) * 32 + kc0 + ks * 2 + kh) * 512);
    };

    bf16x8 bfc[2][4], bfn[2][4];
    stageA(0, 0);
    loadB(bfc, 0);

    for (int ks = 0; ks < 4; ++ks) {
        __syncthreads();
        if (ks + 1 < 4) {
            loadB(bfn, ks + 1);
            stageA((ks + 1) & 1, (ks + 1) * 64);
        }
        const ushort* as = &As[ks & 1][0];
        bf16x8 af[2][2];
        #pragma unroll
        for (int kh = 0; kh < 2; kh++) {
            const int sg = ((kh * 4 + q) ^ rx) * 8;
            #pragma unroll
            for (int i = 0; i < 2; i++)
                af[kh][i] = *(const bf16x8*)&as[(wr + i * 16 + fm) * 64 + sg];
        }
        #pragma unroll
        for (int kh = 0; kh < 2; kh++)
            #pragma unroll
            for (int mi = 0; mi < 2; mi++)
                #pragma unroll
                for (int ni = 0; ni < 4; ni++)
                    acc[mi][ni] = __builtin_amdgcn_mfma_f32_16x16x32_bf16(
                        af[kh][mi], bfc[kh][ni], acc[mi][ni], 0, 0, 0);
        #pragma unroll
        for (int kh = 0; kh < 2; kh++)
            #pragma unroll
            for (int ni = 0; ni < 4; ni++)
                bfc[kh][ni] = bfn[kh][ni];
    }

    const int rr = q * 4;
    #pragma unroll
    for (int ni = 0; ni < 4; ni++) {
        const int col = wc + ni * 16 + fm;
        #pragma unroll
        for (int mi = 0; mi < 2; mi++) {
            const int row = m0 + wr + mi * 16 + rr;
            #pragma unroll
            for (int r = 0; r < 4; r++)
                part[(size_t)(row + r) * ERDIM + col] = f2bf(acc[mi][ni][r]);
        }
    }
}

// ---------------------------------------------------------------------------
// Reduce bf16 split-K partials (4 slabs), apply SCALING*softmax weight,
// write bf16 into Aext[:,1024:1152]. ushort8-vectorized.
// ---------------------------------------------------------------------------
__global__ __launch_bounds__(256) void ax_combine(
    const ushort* __restrict__ part, const float* __restrict__ wgt,
    ushort* __restrict__ Aext)
{
    int g = blockIdx.x * 256 + threadIdx.x;   // 0 .. 65535 (8-elem groups)
    const int t = g >> 4, gr = g & 15;
    const int er0 = gr * 8;
    const int SL = M_TOK * ERDIM;             // 524288
    const int base = t * ERDIM + er0;

    ushort4 p0a = *(const ushort4*)(part + base);
    ushort4 p0b = *(const ushort4*)(part + base + 4);
    ushort4 p1a = *(const ushort4*)(part + base + SL);
    ushort4 p1b = *(const ushort4*)(part + base + SL + 4);
    ushort4 p2a = *(const ushort4*)(part + base + 2 * SL);
    ushort4 p2b = *(const ushort4*)(part + base + 2 * SL + 4);
    ushort4 p3a = *(const ushort4*)(part + base + 3 * SL);
    ushort4 p3b = *(const ushort4*)(part + base + 3 * SL + 4);

    const float w = wgt[t * 8 + (er0 >> 4)];
    ushort o[8];
    o[0] = f2bf((b2f(p0a.x) + b2f(p1a.x) + b2f(p2a.x) + b2f(p3a.x)) * w);
    o[1] = f2bf((b2f(p0a.y) + b2f(p1a.y) + b2f(p2a.y) + b2f(p3a.y)) * w);
    o[2] = f2bf((b2f(p0a.z) + b2f(p1a.z) + b2f(p2a.z) + b2f(p3a.z)) * w);
    o[3] = f2bf((b2f(p0a.w) + b2f(p1a.w) + b2f(p2a.w) + b2f(p3a.w)) * w);
    o[4] = f2bf((b2f(p0b.x) + b2f(p1b.x) + b2f(p2b.x) + b2f(p3b.x)) * w);
    o[5] = f2bf((b2f(p0b.y) + b2f(p1b.y) + b2f(p2b.y) + b2f(p3b.y)) * w);
    o[6] = f2bf((b2f(p0b.z) + b2f(p1b.z) + b2f(p2b.z) + b2f(p3b.z)) * w);
    o[7] = f2bf((b2f(p0b.w) + b2f(p1b.w) + b2f(p2b.w) + b2f(p3b.w)) * w);

    ushort* dst = Aext + (size_t)t * KEXT + KD + er0;
    ((ushort4*)dst)[0] = *(ushort4*)&o[0];
    ((ushort4*)dst)[1] = *(ushort4*)&o[4];
}

// ---------------------------------------------------------------------------
extern "C" void kernel_launch(void* const* d_in, const int* in_sizes, int n_in,
                              void* d_out, int out_size, void* d_ws, size_t ws_size,
                              hipStream_t stream) {
    const float* x        = (const float*)d_in[0];
    const float* base_w   = (const float*)d_in[1];
    const float* base_b   = (const float*)d_in[2];
    const float* lora_A   = (const float*)d_in[3];
    const float* lora_B   = (const float*)d_in[4];
    const float* router_w = (const float*)d_in[5];
    const float* router_b = (const float*)d_in[6];
    float* out = (float*)d_out;

    // workspace layout (bytes): total ~16.4 MB
    char* ws = (char*)d_ws;
    ushort* Aext    = (ushort*)(ws);             // 4096*1152*2 = 9,437,184
    ushort* Bpack   = (ushort*)(ws + 9437184);   // 1024*1152*2 = 2,359,296
    ushort* LATpack = (ushort*)(ws + 11796480);  //  128*1024*2 =   262,144
    float*  wgt     = (float*) (ws + 12058624);  //   4096*8*4  =   131,072
    ushort* part    = (ushort*)(ws + 12189696);  // 4*4096*128*2= 4,194,304

    // 1. fused: router/convert (blocks 0..4095) + dest-linear frag pack
    //    (blocks 4096..4735)
    prep_router<<<4736, 256, 0, stream>>>(
        x, router_w, router_b, base_w, lora_A, lora_B,
        Aext, Bpack, LATpack, wgt);
    // 2. ax = x @ lora_A  (M=4096,N=128,K=1024) split-K=4 -> bf16 partials
    gemm_ax<<<dim3(64, 1, 4), 256, 0, stream>>>(Aext, LATpack, part);
    // 3. sax = bf16(SCALING * w * ax) into Aext[:,1024:1152]
    ax_combine<<<256, 256, 0, stream>>>(part, wgt, Aext);
    // 4. out = [x|sax] @ [base_w|lora_B^T]^T + bias  (M=4096,N=1024,K=1152)
    gemm_main<<<dim3(32, 16), 256, 0, stream>>>(Aext, Bpack, out, base_b);
}